// Round 7
// baseline (118.615 us; speedup 1.0000x reference)
//
#include <hip/hip_runtime.h>
#include <hip/hip_bf16.h>

typedef __attribute__((ext_vector_type(8))) short short8;
typedef __attribute__((ext_vector_type(4))) float f32x4;
typedef __attribute__((ext_vector_type(16))) float f32x16;

__device__ __forceinline__ unsigned short f2bf(float f) {
    unsigned u = __float_as_uint(f);
    unsigned r = (u + 0x7fffu + ((u >> 16) & 1u)) >> 16;
    return (unsigned short)r;
}

// fast GELU (tanh form), NaN-safe: ~14 VALU ops via v_exp_f32.
__device__ __forceinline__ float fast_gelu(float v) {
    float y  = 0.7978845608f * v * (1.0f + 0.044715f * v * v);
    float ay = fabsf(y);
    float e  = __expf(2.0f * ay);
    float th = 1.0f - 2.0f / (e + 1.0f);
    th = __builtin_copysignf(th, y);
    return 0.5f * v * (1.0f + th);
}

// async global->LDS, 16B per lane. LDS dest is wave-uniform base + lane*16.
__device__ __forceinline__ void gload16(const unsigned short* g, unsigned short* l) {
    __builtin_amdgcn_global_load_lds(
        (const __attribute__((address_space(1))) unsigned int*)g,
        (__attribute__((address_space(3))) unsigned int*)l,
        16, 0, 0);
}

// ---------------- prep (blocks 0..623) + LayerNorm1 (blocks 624..4719) -----
__global__ __launch_bounds__(256) void prep_ln1(
    const float* __restrict__ Wq, const float* __restrict__ Wk,
    const float* __restrict__ Wv, const float* __restrict__ Wp,
    const float* __restrict__ W1, const float* __restrict__ W2,
    unsigned short* __restrict__ WqkvT, unsigned short* __restrict__ WpT,
    unsigned short* __restrict__ W1T, unsigned short* __restrict__ W2T,
    const float* __restrict__ xin, const float* __restrict__ gw,
    const float* __restrict__ bw, unsigned short* __restrict__ h1)
{
    __shared__ float smem[4096];
    const int bid = blockIdx.x, t = threadIdx.x;
    if (bid >= 624) {                    // ---- LN1: 4 rows per block
        int row  = (bid - 624) * 4 + (t >> 6);
        int lane = t & 63;
        const float4 v = *reinterpret_cast<const float4*>(xin + (size_t)row * 256 + lane * 4);
        float s  = v.x + v.y + v.z + v.w;
        float sq = v.x*v.x + v.y*v.y + v.z*v.z + v.w*v.w;
#pragma unroll
        for (int m = 1; m < 64; m <<= 1) { s += __shfl_xor(s, m); sq += __shfl_xor(sq, m); }
        float mean = s * (1.0f/256.0f);
        float var  = sq * (1.0f/256.0f) - mean*mean;
        float rstd = rsqrtf(var + 1e-5f);
        const float4 g4 = *reinterpret_cast<const float4*>(gw + lane*4);
        const float4 b4 = *reinterpret_cast<const float4*>(bw + lane*4);
        ushort4 o;
        o.x = f2bf((v.x-mean)*rstd*g4.x + b4.x);
        o.y = f2bf((v.y-mean)*rstd*g4.y + b4.y);
        o.z = f2bf((v.z-mean)*rstd*g4.z + b4.z);
        o.w = f2bf((v.w-mean)*rstd*g4.w + b4.w);
        *reinterpret_cast<ushort4*>(h1 + (size_t)row*256 + lane*4) = o;
        return;
    }
    if (bid < 576) {                     // ---- 32x32 tiled transposes
        const float* W; unsigned short* WT; int N, K, tile0;
        if (bid < 64)       { W = Wp; WT = WpT; N = 256;  K = 256;  tile0 = bid; }
        else if (bid < 320) { W = W1; WT = W1T; N = 1024; K = 256;  tile0 = bid - 64; }
        else                { W = W2; WT = W2T; N = 256;  K = 1024; tile0 = bid - 320; }
        int ntx = N >> 5;
        int bx = tile0 % ntx, by = tile0 / ntx;
        int c0 = bx*32, r0 = by*32;
        int tx = t & 31, ty = t >> 5;
#pragma unroll
        for (int i = 0; i < 4; ++i)
            smem[(ty + i*8)*33 + tx] = W[(size_t)(r0 + ty + i*8)*N + c0 + tx];
        __syncthreads();
#pragma unroll
        for (int i = 0; i < 4; ++i)
            WT[(size_t)(c0 + ty + i*8)*K + r0 + tx] = f2bf(smem[tx*33 + ty + i*8]);
    } else {                             // ---- QKV repack [H,C,HS] -> [768][256]
        int pb = bid - 576;
        int proj = pb >> 4, hh = pb & 15;
        const float* W = (proj == 0) ? Wq : ((proj == 1) ? Wk : Wv);
        float scale = (proj == 0) ? 0.0625f : 1.0f;
        const float4* src = reinterpret_cast<const float4*>(W + hh*4096);
#pragma unroll
        for (int i = 0; i < 4; ++i) {
            float4 v4 = src[t + i*256];
            *reinterpret_cast<float4*>(&smem[(t + i*256)*4]) = v4;
        }
        __syncthreads();
        int d = t >> 4, cp = (t & 15) * 16;
        unsigned short obuf[16];
#pragma unroll
        for (int i = 0; i < 16; ++i)
            obuf[i] = f2bf(smem[(cp + i)*16 + d] * scale);
        unsigned short* dst = WqkvT + (size_t)(proj*256 + hh*16 + d)*256 + cp;
        *reinterpret_cast<ushort4*>(dst)      = *reinterpret_cast<ushort4*>(&obuf[0]);
        *reinterpret_cast<ushort4*>(dst + 4)  = *reinterpret_cast<ushort4*>(&obuf[4]);
        *reinterpret_cast<ushort4*>(dst + 8)  = *reinterpret_cast<ushort4*>(&obuf[8]);
        *reinterpret_cast<ushort4*>(dst + 12) = *reinterpret_cast<ushort4*>(&obuf[12]);
    }
}

// XCD-aware bijective swizzle (T1): 1-D grid, nwg % 8 == 0.
template<int NBX>
__device__ __forceinline__ void swz_bid(int& bx, int& by) {
    int nwg = gridDim.x;
    int bid = blockIdx.x;
    int vid = (bid & 7) * (nwg >> 3) + (bid >> 3);
    bx = vid % NBX;
    by = vid / NBX;
}

// ---------------- GEMM core, 4 waves (2x2), 2-phase dbuf -------------------
template<int BM, int BN, int K>
__device__ __forceinline__ void gemm_core(
    const unsigned short* __restrict__ A, const unsigned short* __restrict__ BT,
    int bx, int by, f32x4 (&acc)[BM/32][BN/32])
{
    constexpr int FM = BM/32, FN = BN/32, NT = K/32;
    __shared__ unsigned short As[2][BM*32];
    __shared__ unsigned short Bs[2][BN*32];
    const int tid = threadIdx.x, lane = tid & 63, wid = tid >> 6;
    const int wr = (wid >> 1) * (BM/2), wc = (wid & 1) * (BN/2);
    const int c16 = lane & 15, g16 = lane >> 4;
    const int lr = lane >> 2, lq = lane & 3;

#pragma unroll
    for (int m = 0; m < FM; ++m)
#pragma unroll
        for (int n = 0; n < FN; ++n) acc[m][n] = f32x4{0.f, 0.f, 0.f, 0.f};

    const unsigned short* a0 = A  + (size_t)(by*BM + lr)*K + lq*8;
    const unsigned short* b0 = BT + (size_t)(bx*BN + lr)*K + lq*8;

    auto stage = [&](int buf, int t) {
        int k0 = t * 32;
#pragma unroll
        for (int i = 0; i < BM/64; ++i) {
            int ch = wid*(BM/64) + i;
            gload16(a0 + (size_t)ch*16*K + k0, &As[buf][ch*512]);
        }
#pragma unroll
        for (int i = 0; i < BN/64; ++i) {
            int ch = wid*(BN/64) + i;
            gload16(b0 + (size_t)ch*16*K + k0, &Bs[buf][ch*512]);
        }
    };

    auto compute = [&](int buf) {
        short8 af[FM], bf[FN];
#pragma unroll
        for (int m = 0; m < FM; ++m)
            af[m] = *reinterpret_cast<const short8*>(&As[buf][(wr + m*16 + c16)*32 + g16*8]);
#pragma unroll
        for (int n = 0; n < FN; ++n)
            bf[n] = *reinterpret_cast<const short8*>(&Bs[buf][(wc + n*16 + c16)*32 + g16*8]);
#pragma unroll
        for (int m = 0; m < FM; ++m)
#pragma unroll
            for (int n = 0; n < FN; ++n)
                acc[m][n] = __builtin_amdgcn_mfma_f32_16x16x32_bf16(af[m], bf[n], acc[m][n], 0, 0, 0);
    };

    stage(0, 0);
    __syncthreads();
    int cur = 0;
    for (int t = 0; t < NT-1; ++t) {
        stage(cur ^ 1, t + 1);
        compute(cur);
        __syncthreads();
        cur ^= 1;
    }
    compute(cur);
}

// ---------------- GEMM core, 8 waves (2Mx4N), 2-phase dbuf -----------------
template<int BM, int BN, int K>
__device__ __forceinline__ void gemm_core8(
    const unsigned short* __restrict__ A, const unsigned short* __restrict__ BT,
    int by, f32x4 (&acc)[BM/32][BN/64])
{
    constexpr int FM = BM/32, FN = BN/64, NT = K/32;
    constexpr int NCHA = BM/16, NCH = BM/16 + BN/16;
    constexpr int NR = (NCH + 7) / 8;
    __shared__ unsigned short As[2][BM*32];
    __shared__ unsigned short Bs[2][BN*32];
    const int tid = threadIdx.x, lane = tid & 63, wid = tid >> 6;
    const int wm = wid >> 2, wn = wid & 3;
    const int c16 = lane & 15, g16 = lane >> 4;
    const int lr = lane >> 2, lq = lane & 3;

#pragma unroll
    for (int m = 0; m < FM; ++m)
#pragma unroll
        for (int n = 0; n < FN; ++n) acc[m][n] = f32x4{0.f, 0.f, 0.f, 0.f};

    const unsigned short* a0 = A  + (size_t)(by*BM + lr)*K + lq*8;
    const unsigned short* b0 = BT + (size_t)lr*K + lq*8;

    auto stage = [&](int buf, int t) {
        int k0 = t * 32;
#pragma unroll
        for (int i = 0; i < NR; ++i) {
            int ch = i*8 + wid;
            if (ch < NCHA)
                gload16(a0 + (size_t)ch*16*K + k0, &As[buf][ch*512]);
            else if (ch < NCH)
                gload16(b0 + (size_t)(ch-NCHA)*16*K + k0, &Bs[buf][(ch-NCHA)*512]);
        }
    };

    auto compute = [&](int buf) {
        short8 af[FM], bf[FN];
#pragma unroll
        for (int m = 0; m < FM; ++m)
            af[m] = *reinterpret_cast<const short8*>(&As[buf][(wm*(BM/2) + m*16 + c16)*32 + g16*8]);
#pragma unroll
        for (int n = 0; n < FN; ++n)
            bf[n] = *reinterpret_cast<const short8*>(&Bs[buf][(wn*(BN/4) + n*16 + c16)*32 + g16*8]);
#pragma unroll
        for (int m = 0; m < FM; ++m)
#pragma unroll
            for (int n = 0; n < FN; ++n)
                acc[m][n] = __builtin_amdgcn_mfma_f32_16x16x32_bf16(af[m], bf[n], acc[m][n], 0, 0, 0);
    };

    stage(0, 0);
    __syncthreads();
    int cur = 0;
    for (int t = 0; t < NT-1; ++t) {
        stage(cur ^ 1, t + 1);
        compute(cur);
        __syncthreads();
        cur ^= 1;
    }
    compute(cur);
}

// QKV GEMM: N=768 = [q|k|v] x 16 heads x 16 dims; scatter epilogue.
__global__ __launch_bounds__(256) void gemm_qkv(
    const unsigned short* __restrict__ A, const unsigned short* __restrict__ BT,
    unsigned short* __restrict__ qb, unsigned short* __restrict__ kb,
    unsigned short* __restrict__ vtb)
{
    int bx, by; swz_bid<6>(bx, by);
    f32x4 acc[4][4];
    gemm_core<128, 128, 256>(A, BT, bx, by, acc);
    const int lane = threadIdx.x & 63, wid = threadIdx.x >> 6;
    const int c16 = lane & 15, g16 = lane >> 4;
    const int wr = (wid >> 1) * 64, wc = (wid & 1) * 64;
#pragma unroll
    for (int m = 0; m < 4; ++m)
#pragma unroll
    for (int n = 0; n < 4; ++n)
#pragma unroll
    for (int j = 0; j < 4; ++j) {
        int row = by*128 + wr + m*16 + g16*4 + j;
        int col = bx*128 + wc + n*16 + c16;
        int proj = col >> 8, hh = (col >> 4) & 15, dd = col & 15;
        int b = row >> 8, t = row & 255;
        unsigned short val = f2bf(acc[m][n][j]);
        size_t bh = (size_t)(b*16 + hh);
        if (proj == 0)      qb[(bh*256 + t)*16 + dd] = val;
        else if (proj == 1) kb[(bh*256 + t)*16 + dd] = val;
        else                vtb[(bh*16 + dd)*256 + t] = val;
    }
}

// proj GEMM + bias + residual -> x2 fp32, fused LN2 -> h2 bf16.
__global__ __launch_bounds__(512) void gemm_wp_ln(
    const unsigned short* __restrict__ A, const unsigned short* __restrict__ BT,
    const float* __restrict__ bp, const float* __restrict__ x,
    const float* __restrict__ g2, const float* __restrict__ be2,
    float* __restrict__ x2, unsigned short* __restrict__ h2)
{
    int bx, by; swz_bid<1>(bx, by);
    f32x4 acc[2][4];
    gemm_core8<64, 256, 256>(A, BT, by, acc);

    __shared__ float rs[64][4];
    __shared__ float rq[64][4];
    const int tid = threadIdx.x, lane = tid & 63, wid = tid >> 6;
    const int c16 = lane & 15, g16 = lane >> 4;
    const int wm = wid >> 2, wn = wid & 3;

    float vv[2][4][4];
#pragma unroll
    for (int m = 0; m < 2; ++m)
#pragma unroll
    for (int n = 0; n < 4; ++n)
#pragma unroll
    for (int j = 0; j < 4; ++j) {
        int row = by*64 + wm*32 + m*16 + g16*4 + j;
        int col = wn*64 + n*16 + c16;
        size_t idx = (size_t)row*256 + col;
        float v = acc[m][n][j] + bp[col] + x[idx];
        vv[m][n][j] = v;
        x2[idx] = v;
    }
#pragma unroll
    for (int m = 0; m < 2; ++m)
#pragma unroll
    for (int j = 0; j < 4; ++j) {
        float ps = vv[m][0][j] + vv[m][1][j] + vv[m][2][j] + vv[m][3][j];
        float pq = vv[m][0][j]*vv[m][0][j] + vv[m][1][j]*vv[m][1][j]
                 + vv[m][2][j]*vv[m][2][j] + vv[m][3][j]*vv[m][3][j];
#pragma unroll
        for (int mask = 1; mask < 16; mask <<= 1) {
            ps += __shfl_xor(ps, mask);
            pq += __shfl_xor(pq, mask);
        }
        if (c16 == 0) {
            int r = wm*32 + m*16 + g16*4 + j;
            rs[r][wn] = ps;
            rq[r][wn] = pq;
        }
    }
    __syncthreads();
#pragma unroll
    for (int m = 0; m < 2; ++m)
#pragma unroll
    for (int j = 0; j < 4; ++j) {
        int r = wm*32 + m*16 + g16*4 + j;
        float s = rs[r][0] + rs[r][1] + rs[r][2] + rs[r][3];
        float q = rq[r][0] + rq[r][1] + rq[r][2] + rq[r][3];
        float mean = s * (1.0f/256.0f);
        float var  = q * (1.0f/256.0f) - mean*mean;
        float rstd = rsqrtf(var + 1e-5f);
        int row = by*64 + r;
#pragma unroll
        for (int n = 0; n < 4; ++n) {
            int col = wn*64 + n*16 + c16;
            h2[(size_t)row*256 + col] = f2bf((vv[m][n][j]-mean)*rstd*g2[col] + be2[col]);
        }
    }
}

// ---------------- Fused FFN: h2 -> GELU(h2 W1 + b1) W2 + b2 + x2 -> out ----
// 256 blocks x 512 thr (8 waves, 2Mx4N). BM=64 rows. 4 hidden chunks of 256.
// Phase1: hid_chunk = GELU(h2[64x256] x W1T_chunk) -> LDS (T2 XOR-swizzled).
// Phase2: out_acc += hid_chunk x W2T K-slice (W2T staged via gload16).
__global__ __launch_bounds__(512) void gemm_ffn_fused(
    const unsigned short* __restrict__ h2, const unsigned short* __restrict__ W1T,
    const unsigned short* __restrict__ W2T, const float* __restrict__ b1,
    const float* __restrict__ b2, const float* __restrict__ x2,
    float* __restrict__ out)
{
    __shared__ unsigned short hid[64*256];      // 32KB, XOR-swizzled rows
    __shared__ unsigned short As[2][64*32];     // 8KB h2 staging
    __shared__ unsigned short Bs[2][256*32];    // 32KB W1T/W2T staging (time-shared)
    char* hidb = (char*)hid;

    int bx_, by; swz_bid<1>(bx_, by);
    const int tid = threadIdx.x, lane = tid & 63, wid = tid >> 6;
    const int wm = wid >> 2, wn = wid & 3;
    const int c16 = lane & 15, g16 = lane >> 4;
    const int lr = lane >> 2, lq = lane & 3;

    const unsigned short* a0 = h2 + (size_t)(by*64 + lr)*256 + lq*8;

    f32x4 oacc[2][4];
#pragma unroll
    for (int m = 0; m < 2; ++m)
#pragma unroll
        for (int n = 0; n < 4; ++n) oacc[m][n] = f32x4{0.f, 0.f, 0.f, 0.f};

    for (int hc = 0; hc < 4; ++hc) {
        // ---------- phase 1: hidden chunk GEMM (K=256, NT=8) ----------
        const unsigned short* b0 = W1T + (size_t)(hc*256 + lr)*256 + lq*8;
        f32x4 pacc[2][4];
#pragma unroll
        for (int m = 0; m < 2; ++m)
#pragma unroll
            for (int n = 0; n < 4; ++n) pacc[m][n] = f32x4{0.f, 0.f, 0.f, 0.f};

        auto stage1 = [&](int buf, int t) {
            int k0 = t * 32;
#pragma unroll
            for (int i = 0; i < 3; ++i) {
                int ch = i*8 + wid;          // 0..23; A chunks 0..3, B chunks 0..15
                if (ch < 4)
                    gload16(a0 + (size_t)ch*16*256 + k0, &As[buf][ch*512]);
                else if (ch < 20)
                    gload16(b0 + (size_t)(ch-4)*16*256 + k0, &Bs[buf][(ch-4)*512]);
            }
        };
        auto compute1 = [&](int buf) {
            short8 af[2], bf[4];
#pragma unroll
            for (int m = 0; m < 2; ++m)
                af[m] = *reinterpret_cast<const short8*>(&As[buf][(wm*32 + m*16 + c16)*32 + g16*8]);
#pragma unroll
            for (int n = 0; n < 4; ++n)
                bf[n] = *reinterpret_cast<const short8*>(&Bs[buf][(wn*64 + n*16 + c16)*32 + g16*8]);
#pragma unroll
            for (int m = 0; m < 2; ++m)
#pragma unroll
                for (int n = 0; n < 4; ++n)
                    pacc[m][n] = __builtin_amdgcn_mfma_f32_16x16x32_bf16(af[m], bf[n], pacc[m][n], 0, 0, 0);
        };

        stage1(0, 0);
        __syncthreads();
        int cur = 0;
        for (int t = 0; t < 7; ++t) {
            stage1(cur ^ 1, t + 1);
            compute1(cur);
            __syncthreads();
            cur ^= 1;
        }
        compute1(cur);
        __syncthreads();                 // Bs free; hid safe to overwrite (prev ph2 done)

        // ---------- GELU -> hid LDS (XOR-swizzle byte ^= (row&7)<<4) ----------
#pragma unroll
        for (int m = 0; m < 2; ++m)
#pragma unroll
        for (int n = 0; n < 4; ++n)
#pragma unroll
        for (int j = 0; j < 4; ++j) {
            int rl = wm*32 + m*16 + g16*4 + j;
            int cl = wn*64 + n*16 + c16;
            float v = pacc[m][n][j] + b1[hc*256 + cl];
            unsigned short g = f2bf(fast_gelu(v));
            *(unsigned short*)(hidb + rl*512 + ((cl*2) ^ ((rl & 7) << 4))) = g;
        }
        __syncthreads();                 // hid chunk complete

        // ---------- phase 2: out_acc += hid x W2T[:, hc*256..+256] ----------
        const unsigned short* b20 = W2T + (size_t)lr*1024 + hc*256 + lq*8;
        auto stage2 = [&](int buf, int kk) {
            int k0 = kk * 32;
#pragma unroll
            for (int i = 0; i < 2; ++i) {
                int ch = i*8 + wid;          // 0..15 (256 rows of W2T)
                gload16(b20 + (size_t)ch*16*1024 + k0, &Bs[buf][ch*512]);
            }
        };
        auto compute2 = [&](int buf, int kk) {
            short8 af[2], bf[4];
#pragma unroll
            for (int m = 0; m < 2; ++m) {
                int rl = wm*32 + m*16 + c16;
                int cb = (kk*32 + g16*8) * 2;
                af[m] = *reinterpret_cast<const short8*>(hidb + rl*512 + (cb ^ ((rl & 7) << 4)));
            }
#pragma unroll
            for (int n = 0; n < 4; ++n)
                bf[n] = *reinterpret_cast<const short8*>(&Bs[buf][(wn*64 + n*16 + c16)*32 + g16*8]);
#pragma unroll
            for (int m = 0; m < 2; ++m)
#pragma unroll
                for (int n = 0; n < 4; ++n)
                    oacc[m][n] = __builtin_amdgcn_mfma_f32_16x16x32_bf16(af[m], bf[n], oacc[m][n], 0, 0, 0);
        };

        stage2(0, 0);
        __syncthreads();
        cur = 0;
        for (int kk = 0; kk < 7; ++kk) {
            stage2(cur ^ 1, kk + 1);
            compute2(cur, kk);
            __syncthreads();
            cur ^= 1;
        }
        compute2(cur, 7);
        __syncthreads();                 // Bs/hid free for next chunk
    }

    // ---------- epilogue: + b2 + residual(x2) -> out ----------
#pragma unroll
    for (int m = 0; m < 2; ++m)
#pragma unroll
    for (int n = 0; n < 4; ++n)
#pragma unroll
    for (int j = 0; j < 4; ++j) {
        int row = by*64 + wm*32 + m*16 + g16*4 + j;
        int col = wn*64 + n*16 + c16;
        size_t idx = (size_t)row*256 + col;
        out[idx] = oacc[m][n][j] + b2[col] + x2[idx];
    }
}

// ---------------- Attention: register-resident, swapped 32x32x16 MFMA -----
__global__ __launch_bounds__(256) void attn_kernel(
    const unsigned short* __restrict__ qb, const unsigned short* __restrict__ kb,
    const unsigned short* __restrict__ vtb, unsigned short* __restrict__ ao)
{
    const int bid  = blockIdx.x;
    const int half = bid & 1, h = (bid >> 1) & 15, b = bid >> 5;
    const int tid  = threadIdx.x;
    const int w    = tid >> 6, lane = tid & 63;
    const int l31  = lane & 31, hi = lane >> 5;
    const int chunk = half*4 + w;
    const int t0    = chunk * 32;
    const unsigned short* qh = qb  + (size_t)(b*16 + h) * 4096;
    const unsigned short* kh = kb  + (size_t)(b*16 + h) * 4096;
    const unsigned short* vh = vtb + (size_t)(b*16 + h) * 4096;

    short8 qf = *reinterpret_cast<const short8*>(qh + (size_t)(t0 + l31)*16 + hi*8);

    f32x16 zf, pv;
#pragma unroll
    for (int i = 0; i < 16; ++i) { zf[i] = 0.f; pv[i] = 0.f; }
    float sum = 0.f;
    const int dref = l31 & 15;

    for (int tt = 0; tt <= chunk; ++tt) {
        short8 kf = *reinterpret_cast<const short8*>(kh + (size_t)(tt*32 + l31)*16 + hi*8);
        f32x16 S = __builtin_amdgcn_mfma_f32_32x32x16_bf16(kf, qf, zf, 0, 0, 0);

        float p[16];
#pragma unroll
        for (int r = 0; r < 16; ++r) {
            float pe = __expf(S[r]);
            if (tt == chunk) {
                int s_local = (r & 3) + 8*(r >> 2) + 4*hi;
                pe = (s_local <= l31) ? pe : 0.f;
            }
            p[r] = pe;
            sum += pe;
        }

        unsigned qd[8], xd[8];
#pragma unroll
        for (int i = 0; i < 8; ++i) {
            unsigned rr;
            asm("v_cvt_pk_bf16_f32 %0, %1, %2" : "=v"(rr) : "v"(p[2*i]), "v"(p[2*i+1]));
            qd[i] = rr;
        }
#pragma unroll
        for (int i = 0; i < 8; ++i) xd[i] = (unsigned)__shfl_xor((int)qd[i], 32);

        int4 flo, fhi;
        flo.x = hi ? (int)xd[2] : (int)qd[0];
        flo.y = hi ? (int)xd[3] : (int)qd[1];
        flo.z = hi ? (int)qd[2] : (int)xd[0];
        flo.w = hi ? (int)qd[3] : (int)xd[1];
        fhi.x = hi ? (int)xd[6] : (int)qd[4];
        fhi.y = hi ? (int)xd[7] : (int)qd[5];
        fhi.z = hi ? (int)qd[6] : (int)xd[4];
        fhi.w = hi ? (int)qd[7] : (int)xd[5];
        short8 plo = __builtin_bit_cast(short8, flo);
        short8 phi = __builtin_bit_cast(short8, fhi);

        short8 vf0 = *reinterpret_cast<const short8*>(vh + (size_t)dref*256 + tt*32 + hi*8);
        short8 vf1 = *reinterpret_cast<const short8*>(vh + (size_t)dref*256 + tt*32 + 16 + hi*8);
        pv = __builtin_amdgcn_mfma_f32_32x32x16_bf16(vf0, plo, pv, 0, 0, 0);
        pv = __builtin_amdgcn_mfma_f32_32x32x16_bf16(vf1, phi, pv, 0, 0, 0);
    }

    sum += __shfl_xor(sum, 32);
    float rinv = 1.0f / sum;

    unsigned o0, o1, o2, o3;
    {
        float a0 = pv[0]*rinv, a1 = pv[1]*rinv, a2 = pv[2]*rinv, a3 = pv[3]*rinv;
        float a4 = pv[4]*rinv, a5 = pv[5]*rinv, a6 = pv[6]*rinv, a7 = pv[7]*rinv;
        asm("v_cvt_pk_bf16_f32 %0, %1, %2" : "=v"(o0) : "v"(a0), "v"(a1));
        asm("v_cvt_pk_bf16_f32 %0, %1, %2" : "=v"(o1) : "v"(a2), "v"(a3));
        asm("v_cvt_pk_bf16_f32 %0, %1, %2" : "=v"(o2) : "v"(a4), "v"(a5));
        asm("v_cvt_pk_bf16_f32 %0, %1, %2" : "=v"(o3) : "v"(a6), "v"(a7));
    }
    unsigned short* orow = ao + (size_t)(b*256 + t0 + l31)*256 + h*16;
    uint2 s01 = {o0, o1}, s23 = {o2, o3};
    *reinterpret_cast<uint2*>(orow + hi*4)     = s01;
    *reinterpret_cast<uint2*>(orow + 8 + hi*4) = s23;
}

// ---------------- launch ---------------------------------------------------
extern "C" void kernel_launch(void* const* d_in, const int* in_sizes, int n_in,
                              void* d_out, int out_size, void* d_ws, size_t ws_size,
                              hipStream_t stream)
{
    const float* x   = (const float*)d_in[0];
    const float* Wq  = (const float*)d_in[1];
    const float* Wk  = (const float*)d_in[2];
    const float* Wv  = (const float*)d_in[3];
    const float* Wp  = (const float*)d_in[4];
    const float* bp  = (const float*)d_in[5];
    const float* W1  = (const float*)d_in[6];
    const float* b1  = (const float*)d_in[7];
    const float* W2  = (const float*)d_in[8];
    const float* b2  = (const float*)d_in[9];
    const float* g1  = (const float*)d_in[10];
    const float* be1 = (const float*)d_in[11];
    const float* g2  = (const float*)d_in[12];
    const float* be2 = (const float*)d_in[13];
    float* out = (float*)d_out;

    char* ws = (char*)d_ws;
    unsigned short* h1    = (unsigned short*)(ws);
    unsigned short* WqkvT = (unsigned short*)(ws +  8388608);
    unsigned short* WpT   = (unsigned short*)(ws +  8781824);
    unsigned short* W1T   = (unsigned short*)(ws +  8912896);
    unsigned short* W2T   = (unsigned short*)(ws +  9437184);
    unsigned short* qb    = (unsigned short*)(ws +  9961472);
    unsigned short* kb    = (unsigned short*)(ws + 18350080);
    unsigned short* vtb   = (unsigned short*)(ws + 26738688);
    unsigned short* ao    = (unsigned short*)(ws + 35127296);
    float*          x2    = (float*)(ws + 43515904);
    unsigned short* h2    = (unsigned short*)(ws + 60293120);

    prep_ln1<<<4720, 256, 0, stream>>>(Wq, Wk, Wv, Wp, W1, W2,
                                       WqkvT, WpT, W1T, W2T, x, g1, be1, h1);
    gemm_qkv<<<768, 256, 0, stream>>>(h1, WqkvT, qb, kb, vtb);
    attn_kernel<<<2048, 256, 0, stream>>>(qb, kb, vtb, ao);
    gemm_wp_ln<<<256, 512, 0, stream>>>(ao, WpT, bp, x, g2, be2, x2, h2);
    gemm_ffn_fused<<<256, 512, 0, stream>>>(h2, W1T, W2T, b1, b2, x2, out);
}

// Round 8
// 114.726 us; speedup vs baseline: 1.0339x; 1.0339x over previous
//
#include <hip/hip_runtime.h>
#include <hip/hip_bf16.h>

typedef __attribute__((ext_vector_type(8))) short short8;
typedef __attribute__((ext_vector_type(4))) float f32x4;
typedef __attribute__((ext_vector_type(16))) float f32x16;

__device__ __forceinline__ unsigned short f2bf(float f) {
    unsigned u = __float_as_uint(f);
    unsigned r = (u + 0x7fffu + ((u >> 16) & 1u)) >> 16;
    return (unsigned short)r;
}
__device__ __forceinline__ float bf2f(unsigned short h) {
    return __uint_as_float(((unsigned)h) << 16);
}

// fast GELU (tanh form), NaN-safe: ~14 VALU ops via v_exp_f32.
__device__ __forceinline__ float fast_gelu(float v) {
    float y  = 0.7978845608f * v * (1.0f + 0.044715f * v * v);
    float ay = fabsf(y);
    float e  = __expf(2.0f * ay);
    float th = 1.0f - 2.0f / (e + 1.0f);
    th = __builtin_copysignf(th, y);
    return 0.5f * v * (1.0f + th);
}

// async global->LDS, 16B per lane. LDS dest is wave-uniform base + lane*16.
__device__ __forceinline__ void gload16(const unsigned short* g, unsigned short* l) {
    __builtin_amdgcn_global_load_lds(
        (const __attribute__((address_space(1))) unsigned int*)g,
        (__attribute__((address_space(3))) unsigned int*)l,
        16, 0, 0);
}

// ---------------- prep (blocks 0..623) + LayerNorm1 (blocks 624..4719) -----
__global__ __launch_bounds__(256) void prep_ln1(
    const float* __restrict__ Wq, const float* __restrict__ Wk,
    const float* __restrict__ Wv, const float* __restrict__ Wp,
    const float* __restrict__ W1, const float* __restrict__ W2,
    unsigned short* __restrict__ WqkvT, unsigned short* __restrict__ WpT,
    unsigned short* __restrict__ W1T, unsigned short* __restrict__ W2T,
    const float* __restrict__ xin, const float* __restrict__ gw,
    const float* __restrict__ bw, unsigned short* __restrict__ h1)
{
    __shared__ float smem[4096];
    const int bid = blockIdx.x, t = threadIdx.x;
    if (bid >= 624) {                    // ---- LN1: 4 rows per block
        int row  = (bid - 624) * 4 + (t >> 6);
        int lane = t & 63;
        const float4 v = *reinterpret_cast<const float4*>(xin + (size_t)row * 256 + lane * 4);
        float s  = v.x + v.y + v.z + v.w;
        float sq = v.x*v.x + v.y*v.y + v.z*v.z + v.w*v.w;
#pragma unroll
        for (int m = 1; m < 64; m <<= 1) { s += __shfl_xor(s, m); sq += __shfl_xor(sq, m); }
        float mean = s * (1.0f/256.0f);
        float var  = sq * (1.0f/256.0f) - mean*mean;
        float rstd = rsqrtf(var + 1e-5f);
        const float4 g4 = *reinterpret_cast<const float4*>(gw + lane*4);
        const float4 b4 = *reinterpret_cast<const float4*>(bw + lane*4);
        ushort4 o;
        o.x = f2bf((v.x-mean)*rstd*g4.x + b4.x);
        o.y = f2bf((v.y-mean)*rstd*g4.y + b4.y);
        o.z = f2bf((v.z-mean)*rstd*g4.z + b4.z);
        o.w = f2bf((v.w-mean)*rstd*g4.w + b4.w);
        *reinterpret_cast<ushort4*>(h1 + (size_t)row*256 + lane*4) = o;
        return;
    }
    if (bid < 576) {                     // ---- 32x32 tiled transposes
        const float* W; unsigned short* WT; int N, K, tile0;
        if (bid < 64)       { W = Wp; WT = WpT; N = 256;  K = 256;  tile0 = bid; }
        else if (bid < 320) { W = W1; WT = W1T; N = 1024; K = 256;  tile0 = bid - 64; }
        else                { W = W2; WT = W2T; N = 256;  K = 1024; tile0 = bid - 320; }
        int ntx = N >> 5;
        int bx = tile0 % ntx, by = tile0 / ntx;
        int c0 = bx*32, r0 = by*32;
        int tx = t & 31, ty = t >> 5;
#pragma unroll
        for (int i = 0; i < 4; ++i)
            smem[(ty + i*8)*33 + tx] = W[(size_t)(r0 + ty + i*8)*N + c0 + tx];
        __syncthreads();
#pragma unroll
        for (int i = 0; i < 4; ++i)
            WT[(size_t)(c0 + ty + i*8)*K + r0 + tx] = f2bf(smem[tx*33 + ty + i*8]);
    } else {                             // ---- QKV repack [H,C,HS] -> [768][256]
        int pb = bid - 576;
        int proj = pb >> 4, hh = pb & 15;
        const float* W = (proj == 0) ? Wq : ((proj == 1) ? Wk : Wv);
        float scale = (proj == 0) ? 0.0625f : 1.0f;
        const float4* src = reinterpret_cast<const float4*>(W + hh*4096);
#pragma unroll
        for (int i = 0; i < 4; ++i) {
            float4 v4 = src[t + i*256];
            *reinterpret_cast<float4*>(&smem[(t + i*256)*4]) = v4;
        }
        __syncthreads();
        int d = t >> 4, cp = (t & 15) * 16;
        unsigned short obuf[16];
#pragma unroll
        for (int i = 0; i < 16; ++i)
            obuf[i] = f2bf(smem[(cp + i)*16 + d] * scale);
        unsigned short* dst = WqkvT + (size_t)(proj*256 + hh*16 + d)*256 + cp;
        *reinterpret_cast<ushort4*>(dst)      = *reinterpret_cast<ushort4*>(&obuf[0]);
        *reinterpret_cast<ushort4*>(dst + 4)  = *reinterpret_cast<ushort4*>(&obuf[4]);
        *reinterpret_cast<ushort4*>(dst + 8)  = *reinterpret_cast<ushort4*>(&obuf[8]);
        *reinterpret_cast<ushort4*>(dst + 12) = *reinterpret_cast<ushort4*>(&obuf[12]);
    }
}

// XCD-aware bijective swizzle (T1): 1-D grid, nwg % 8 == 0.
template<int NBX>
__device__ __forceinline__ void swz_bid(int& bx, int& by) {
    int nwg = gridDim.x;
    int bid = blockIdx.x;
    int vid = (bid & 7) * (nwg >> 3) + (bid >> 3);
    bx = vid % NBX;
    by = vid / NBX;
}

// ---------------- GEMM core, 4 waves (2x2), 2-phase dbuf -------------------
template<int BM, int BN, int K>
__device__ __forceinline__ void gemm_core(
    const unsigned short* __restrict__ A, const unsigned short* __restrict__ BT,
    int bx, int by, f32x4 (&acc)[BM/32][BN/32])
{
    constexpr int FM = BM/32, FN = BN/32, NT = K/32;
    __shared__ unsigned short As[2][BM*32];
    __shared__ unsigned short Bs[2][BN*32];
    const int tid = threadIdx.x, lane = tid & 63, wid = tid >> 6;
    const int wr = (wid >> 1) * (BM/2), wc = (wid & 1) * (BN/2);
    const int c16 = lane & 15, g16 = lane >> 4;
    const int lr = lane >> 2, lq = lane & 3;

#pragma unroll
    for (int m = 0; m < FM; ++m)
#pragma unroll
        for (int n = 0; n < FN; ++n) acc[m][n] = f32x4{0.f, 0.f, 0.f, 0.f};

    const unsigned short* a0 = A  + (size_t)(by*BM + lr)*K + lq*8;
    const unsigned short* b0 = BT + (size_t)(bx*BN + lr)*K + lq*8;

    auto stage = [&](int buf, int t) {
        int k0 = t * 32;
#pragma unroll
        for (int i = 0; i < BM/64; ++i) {
            int ch = wid*(BM/64) + i;
            gload16(a0 + (size_t)ch*16*K + k0, &As[buf][ch*512]);
        }
#pragma unroll
        for (int i = 0; i < BN/64; ++i) {
            int ch = wid*(BN/64) + i;
            gload16(b0 + (size_t)ch*16*K + k0, &Bs[buf][ch*512]);
        }
    };

    auto compute = [&](int buf) {
        short8 af[FM], bf[FN];
#pragma unroll
        for (int m = 0; m < FM; ++m)
            af[m] = *reinterpret_cast<const short8*>(&As[buf][(wr + m*16 + c16)*32 + g16*8]);
#pragma unroll
        for (int n = 0; n < FN; ++n)
            bf[n] = *reinterpret_cast<const short8*>(&Bs[buf][(wc + n*16 + c16)*32 + g16*8]);
#pragma unroll
        for (int m = 0; m < FM; ++m)
#pragma unroll
            for (int n = 0; n < FN; ++n)
                acc[m][n] = __builtin_amdgcn_mfma_f32_16x16x32_bf16(af[m], bf[n], acc[m][n], 0, 0, 0);
    };

    stage(0, 0);
    __syncthreads();
    int cur = 0;
    for (int t = 0; t < NT-1; ++t) {
        stage(cur ^ 1, t + 1);
        compute(cur);
        __syncthreads();
        cur ^= 1;
    }
    compute(cur);
}

// ---------------- GEMM core, 8 waves (2Mx4N), BN=256 panels, 2-phase dbuf --
template<int BM, int BN, int K>
__device__ __forceinline__ void gemm_core8(
    const unsigned short* __restrict__ A, const unsigned short* __restrict__ BT,
    int bx, int by, f32x4 (&acc)[BM/32][BN/64])
{
    constexpr int FM = BM/32, FN = BN/64, NT = K/32;
    constexpr int NCHA = BM/16, NCH = BM/16 + BN/16;
    constexpr int NR = (NCH + 7) / 8;
    __shared__ unsigned short As[2][BM*32];
    __shared__ unsigned short Bs[2][BN*32];
    const int tid = threadIdx.x, lane = tid & 63, wid = tid >> 6;
    const int wm = wid >> 2, wn = wid & 3;
    const int c16 = lane & 15, g16 = lane >> 4;
    const int lr = lane >> 2, lq = lane & 3;

#pragma unroll
    for (int m = 0; m < FM; ++m)
#pragma unroll
        for (int n = 0; n < FN; ++n) acc[m][n] = f32x4{0.f, 0.f, 0.f, 0.f};

    const unsigned short* a0 = A  + (size_t)(by*BM + lr)*K + lq*8;
    const unsigned short* b0 = BT + (size_t)(bx*BN + lr)*K + lq*8;

    auto stage = [&](int buf, int t) {
        int k0 = t * 32;
#pragma unroll
        for (int i = 0; i < NR; ++i) {
            int ch = i*8 + wid;
            if (ch < NCHA)
                gload16(a0 + (size_t)ch*16*K + k0, &As[buf][ch*512]);
            else if (ch < NCH)
                gload16(b0 + (size_t)(ch-NCHA)*16*K + k0, &Bs[buf][(ch-NCHA)*512]);
        }
    };

    auto compute = [&](int buf) {
        short8 af[FM], bf[FN];
#pragma unroll
        for (int m = 0; m < FM; ++m)
            af[m] = *reinterpret_cast<const short8*>(&As[buf][(wm*(BM/2) + m*16 + c16)*32 + g16*8]);
#pragma unroll
        for (int n = 0; n < FN; ++n)
            bf[n] = *reinterpret_cast<const short8*>(&Bs[buf][(wn*(BN/4) + n*16 + c16)*32 + g16*8]);
#pragma unroll
        for (int m = 0; m < FM; ++m)
#pragma unroll
            for (int n = 0; n < FN; ++n)
                acc[m][n] = __builtin_amdgcn_mfma_f32_16x16x32_bf16(af[m], bf[n], acc[m][n], 0, 0, 0);
    };

    stage(0, 0);
    __syncthreads();
    int cur = 0;
    for (int t = 0; t < NT-1; ++t) {
        stage(cur ^ 1, t + 1);
        compute(cur);
        __syncthreads();
        cur ^= 1;
    }
    compute(cur);
}

// QKV GEMM: N=768 = [q|k|v] x 16 heads x 16 dims; scatter epilogue.
__global__ __launch_bounds__(256) void gemm_qkv(
    const unsigned short* __restrict__ A, const unsigned short* __restrict__ BT,
    unsigned short* __restrict__ qb, unsigned short* __restrict__ kb,
    unsigned short* __restrict__ vtb)
{
    int bx, by; swz_bid<6>(bx, by);
    f32x4 acc[4][4];
    gemm_core<128, 128, 256>(A, BT, bx, by, acc);
    const int lane = threadIdx.x & 63, wid = threadIdx.x >> 6;
    const int c16 = lane & 15, g16 = lane >> 4;
    const int wr = (wid >> 1) * 64, wc = (wid & 1) * 64;
#pragma unroll
    for (int m = 0; m < 4; ++m)
#pragma unroll
    for (int n = 0; n < 4; ++n)
#pragma unroll
    for (int j = 0; j < 4; ++j) {
        int row = by*128 + wr + m*16 + g16*4 + j;
        int col = bx*128 + wc + n*16 + c16;
        int proj = col >> 8, hh = (col >> 4) & 15, dd = col & 15;
        int b = row >> 8, t = row & 255;
        unsigned short val = f2bf(acc[m][n][j]);
        size_t bh = (size_t)(b*16 + hh);
        if (proj == 0)      qb[(bh*256 + t)*16 + dd] = val;
        else if (proj == 1) kb[(bh*256 + t)*16 + dd] = val;
        else                vtb[(bh*16 + dd)*256 + t] = val;
    }
}

// proj GEMM + bias + residual -> x2 bf16, fused LN2 -> h2 bf16.
__global__ __launch_bounds__(512) void gemm_wp_ln(
    const unsigned short* __restrict__ A, const unsigned short* __restrict__ BT,
    const float* __restrict__ bp, const float* __restrict__ x,
    const float* __restrict__ g2, const float* __restrict__ be2,
    unsigned short* __restrict__ x2b, unsigned short* __restrict__ h2)
{
    int bx, by; swz_bid<1>(bx, by);
    f32x4 acc[2][4];
    gemm_core8<64, 256, 256>(A, BT, 0, by, acc);

    __shared__ float rs[64][4];
    __shared__ float rq[64][4];
    const int tid = threadIdx.x, lane = tid & 63, wid = tid >> 6;
    const int c16 = lane & 15, g16 = lane >> 4;
    const int wm = wid >> 2, wn = wid & 3;

    float vv[2][4][4];
#pragma unroll
    for (int m = 0; m < 2; ++m)
#pragma unroll
    for (int n = 0; n < 4; ++n)
#pragma unroll
    for (int j = 0; j < 4; ++j) {
        int row = by*64 + wm*32 + m*16 + g16*4 + j;
        int col = wn*64 + n*16 + c16;
        size_t idx = (size_t)row*256 + col;
        float v = acc[m][n][j] + bp[col] + x[idx];
        vv[m][n][j] = v;
        x2b[idx] = f2bf(v);
    }
#pragma unroll
    for (int m = 0; m < 2; ++m)
#pragma unroll
    for (int j = 0; j < 4; ++j) {
        float ps = vv[m][0][j] + vv[m][1][j] + vv[m][2][j] + vv[m][3][j];
        float pq = vv[m][0][j]*vv[m][0][j] + vv[m][1][j]*vv[m][1][j]
                 + vv[m][2][j]*vv[m][2][j] + vv[m][3][j]*vv[m][3][j];
#pragma unroll
        for (int mask = 1; mask < 16; mask <<= 1) {
            ps += __shfl_xor(ps, mask);
            pq += __shfl_xor(pq, mask);
        }
        if (c16 == 0) {
            int r = wm*32 + m*16 + g16*4 + j;
            rs[r][wn] = ps;
            rq[r][wn] = pq;
        }
    }
    __syncthreads();
#pragma unroll
    for (int m = 0; m < 2; ++m)
#pragma unroll
    for (int j = 0; j < 4; ++j) {
        int r = wm*32 + m*16 + g16*4 + j;
        float s = rs[r][0] + rs[r][1] + rs[r][2] + rs[r][3];
        float q = rq[r][0] + rq[r][1] + rq[r][2] + rq[r][3];
        float mean = s * (1.0f/256.0f);
        float var  = q * (1.0f/256.0f) - mean*mean;
        float rstd = rsqrtf(var + 1e-5f);
        int row = by*64 + r;
#pragma unroll
        for (int n = 0; n < 4; ++n) {
            int col = wn*64 + n*16 + c16;
            h2[(size_t)row*256 + col] = f2bf((vv[m][n][j]-mean)*rstd*g2[col] + be2[col]);
        }
    }
}

// FFN1 GEMM + bias + fast GELU -> bf16 [16384][1024]. 8 waves, 128x256 tile.
__global__ __launch_bounds__(512) void gemm_ffn1(
    const unsigned short* __restrict__ A, const unsigned short* __restrict__ BT,
    const float* __restrict__ b1, unsigned short* __restrict__ ffh)
{
    int bx, by; swz_bid<4>(bx, by);
    f32x4 acc[4][4];
    gemm_core8<128, 256, 256>(A, BT, bx, by, acc);
    const int lane = threadIdx.x & 63, wid = threadIdx.x >> 6;
    const int c16 = lane & 15, g16 = lane >> 4;
    const int wm = wid >> 2, wn = wid & 3;
#pragma unroll
    for (int m = 0; m < 4; ++m)
#pragma unroll
    for (int n = 0; n < 4; ++n)
#pragma unroll
    for (int j = 0; j < 4; ++j) {
        int row = by*128 + wm*64 + m*16 + g16*4 + j;
        int col = bx*256 + wn*64 + n*16 + c16;
        float v = acc[m][n][j] + b1[col];
        ffh[(size_t)row*1024 + col] = f2bf(fast_gelu(v));
    }
}

// FFN2 GEMM + bias + residual(x2 bf16) -> fp32 out. BM=64, BN=256, K=1024.
__global__ __launch_bounds__(512) void gemm_ffn2(
    const unsigned short* __restrict__ A, const unsigned short* __restrict__ BT,
    const float* __restrict__ b2, const unsigned short* __restrict__ x2b,
    float* __restrict__ out)
{
    int bx, by; swz_bid<1>(bx, by);
    f32x4 acc[2][4];
    gemm_core8<64, 256, 1024>(A, BT, 0, by, acc);
    const int lane = threadIdx.x & 63, wid = threadIdx.x >> 6;
    const int c16 = lane & 15, g16 = lane >> 4;
    const int wm = wid >> 2, wn = wid & 3;
#pragma unroll
    for (int m = 0; m < 2; ++m)
#pragma unroll
    for (int n = 0; n < 4; ++n)
#pragma unroll
    for (int j = 0; j < 4; ++j) {
        int row = by*64 + wm*32 + m*16 + g16*4 + j;
        int col = wn*64 + n*16 + c16;
        size_t idx = (size_t)row*256 + col;
        out[idx] = acc[m][n][j] + b2[col] + bf2f(x2b[idx]);
    }
}

// ---------------- Attention: register-resident, swapped 32x32x16 MFMA -----
__global__ __launch_bounds__(256) void attn_kernel(
    const unsigned short* __restrict__ qb, const unsigned short* __restrict__ kb,
    const unsigned short* __restrict__ vtb, unsigned short* __restrict__ ao)
{
    const int bid  = blockIdx.x;
    const int half = bid & 1, h = (bid >> 1) & 15, b = bid >> 5;
    const int tid  = threadIdx.x;
    const int w    = tid >> 6, lane = tid & 63;
    const int l31  = lane & 31, hi = lane >> 5;
    const int chunk = half*4 + w;
    const int t0    = chunk * 32;
    const unsigned short* qh = qb  + (size_t)(b*16 + h) * 4096;
    const unsigned short* kh = kb  + (size_t)(b*16 + h) * 4096;
    const unsigned short* vh = vtb + (size_t)(b*16 + h) * 4096;

    short8 qf = *reinterpret_cast<const short8*>(qh + (size_t)(t0 + l31)*16 + hi*8);

    f32x16 zf, pv;
#pragma unroll
    for (int i = 0; i < 16; ++i) { zf[i] = 0.f; pv[i] = 0.f; }
    float sum = 0.f;
    const int dref = l31 & 15;

    for (int tt = 0; tt <= chunk; ++tt) {
        short8 kf = *reinterpret_cast<const short8*>(kh + (size_t)(tt*32 + l31)*16 + hi*8);
        f32x16 S = __builtin_amdgcn_mfma_f32_32x32x16_bf16(kf, qf, zf, 0, 0, 0);

        float p[16];
#pragma unroll
        for (int r = 0; r < 16; ++r) {
            float pe = __expf(S[r]);
            if (tt == chunk) {
                int s_local = (r & 3) + 8*(r >> 2) + 4*hi;
                pe = (s_local <= l31) ? pe : 0.f;
            }
            p[r] = pe;
            sum += pe;
        }

        unsigned qd[8], xd[8];
#pragma unroll
        for (int i = 0; i < 8; ++i) {
            unsigned rr;
            asm("v_cvt_pk_bf16_f32 %0, %1, %2" : "=v"(rr) : "v"(p[2*i]), "v"(p[2*i+1]));
            qd[i] = rr;
        }
#pragma unroll
        for (int i = 0; i < 8; ++i) xd[i] = (unsigned)__shfl_xor((int)qd[i], 32);

        int4 flo, fhi;
        flo.x = hi ? (int)xd[2] : (int)qd[0];
        flo.y = hi ? (int)xd[3] : (int)qd[1];
        flo.z = hi ? (int)qd[2] : (int)xd[0];
        flo.w = hi ? (int)qd[3] : (int)xd[1];
        fhi.x = hi ? (int)xd[6] : (int)qd[4];
        fhi.y = hi ? (int)xd[7] : (int)qd[5];
        fhi.z = hi ? (int)qd[6] : (int)xd[4];
        fhi.w = hi ? (int)qd[7] : (int)xd[5];
        short8 plo = __builtin_bit_cast(short8, flo);
        short8 phi = __builtin_bit_cast(short8, fhi);

        short8 vf0 = *reinterpret_cast<const short8*>(vh + (size_t)dref*256 + tt*32 + hi*8);
        short8 vf1 = *reinterpret_cast<const short8*>(vh + (size_t)dref*256 + tt*32 + 16 + hi*8);
        pv = __builtin_amdgcn_mfma_f32_32x32x16_bf16(vf0, plo, pv, 0, 0, 0);
        pv = __builtin_amdgcn_mfma_f32_32x32x16_bf16(vf1, phi, pv, 0, 0, 0);
    }

    sum += __shfl_xor(sum, 32);
    float rinv = 1.0f / sum;

    unsigned o0, o1, o2, o3;
    {
        float a0 = pv[0]*rinv, a1 = pv[1]*rinv, a2 = pv[2]*rinv, a3 = pv[3]*rinv;
        float a4 = pv[4]*rinv, a5 = pv[5]*rinv, a6 = pv[6]*rinv, a7 = pv[7]*rinv;
        asm("v_cvt_pk_bf16_f32 %0, %1, %2" : "=v"(o0) : "v"(a0), "v"(a1));
        asm("v_cvt_pk_bf16_f32 %0, %1, %2" : "=v"(o1) : "v"(a2), "v"(a3));
        asm("v_cvt_pk_bf16_f32 %0, %1, %2" : "=v"(o2) : "v"(a4), "v"(a5));
        asm("v_cvt_pk_bf16_f32 %0, %1, %2" : "=v"(o3) : "v"(a6), "v"(a7));
    }
    unsigned short* orow = ao + (size_t)(b*256 + t0 + l31)*256 + h*16;
    uint2 s01 = {o0, o1}, s23 = {o2, o3};
    *reinterpret_cast<uint2*>(orow + hi*4)     = s01;
    *reinterpret_cast<uint2*>(orow + 8 + hi*4) = s23;
}

// ---------------- launch ---------------------------------------------------
extern "C" void kernel_launch(void* const* d_in, const int* in_sizes, int n_in,
                              void* d_out, int out_size, void* d_ws, size_t ws_size,
                              hipStream_t stream)
{
    const float* x   = (const float*)d_in[0];
    const float* Wq  = (const float*)d_in[1];
    const float* Wk  = (const float*)d_in[2];
    const float* Wv  = (const float*)d_in[3];
    const float* Wp  = (const float*)d_in[4];
    const float* bp  = (const float*)d_in[5];
    const float* W1  = (const float*)d_in[6];
    const float* b1  = (const float*)d_in[7];
    const float* W2  = (const float*)d_in[8];
    const float* b2  = (const float*)d_in[9];
    const float* g1  = (const float*)d_in[10];
    const float* be1 = (const float*)d_in[11];
    const float* g2  = (const float*)d_in[12];
    const float* be2 = (const float*)d_in[13];
    float* out = (float*)d_out;

    char* ws = (char*)d_ws;
    unsigned short* h1    = (unsigned short*)(ws);
    unsigned short* WqkvT = (unsigned short*)(ws +  8388608);
    unsigned short* WpT   = (unsigned short*)(ws +  8781824);
    unsigned short* W1T   = (unsigned short*)(ws +  8912896);
    unsigned short* W2T   = (unsigned short*)(ws +  9437184);
    unsigned short* qb    = (unsigned short*)(ws +  9961472);
    unsigned short* kb    = (unsigned short*)(ws + 18350080);
    unsigned short* vtb   = (unsigned short*)(ws + 26738688);
    unsigned short* ao    = (unsigned short*)(ws + 35127296);
    unsigned short* ffh   = qb;                       // aliases qb..ao (dead by FFN1)
    unsigned short* x2b   = (unsigned short*)(ws + 43515904);
    unsigned short* h2    = (unsigned short*)(ws + 60293120);

    prep_ln1<<<4720, 256, 0, stream>>>(Wq, Wk, Wv, Wp, W1, W2,
                                       WqkvT, WpT, W1T, W2T, x, g1, be1, h1);
    gemm_qkv<<<768, 256, 0, stream>>>(h1, WqkvT, qb, kb, vtb);
    attn_kernel<<<2048, 256, 0, stream>>>(qb, kb, vtb, ao);
    gemm_wp_ln<<<256, 512, 0, stream>>>(ao, WpT, bp, x, g2, be2, x2b, h2);
    gemm_ffn1<<<512, 512, 0, stream>>>(h2, W1T, b1, ffh);
    gemm_ffn2<<<256, 512, 0, stream>>>(ffh, W2T, b2, x2b, out);
}

// Round 9
// 109.188 us; speedup vs baseline: 1.0863x; 1.0507x over previous
//
#include <hip/hip_runtime.h>
#include <hip/hip_bf16.h>

typedef __attribute__((ext_vector_type(8))) short short8;
typedef __attribute__((ext_vector_type(4))) float f32x4;
typedef __attribute__((ext_vector_type(16))) float f32x16;

__device__ __forceinline__ unsigned short f2bf(float f) {
    unsigned u = __float_as_uint(f);
    unsigned r = (u + 0x7fffu + ((u >> 16) & 1u)) >> 16;
    return (unsigned short)r;
}
__device__ __forceinline__ float bf2f(unsigned short h) {
    return __uint_as_float(((unsigned)h) << 16);
}

// fast GELU (tanh form), NaN-safe: ~14 VALU ops via v_exp_f32.
__device__ __forceinline__ float fast_gelu(float v) {
    float y  = 0.7978845608f * v * (1.0f + 0.044715f * v * v);
    float ay = fabsf(y);
    float e  = __expf(2.0f * ay);
    float th = 1.0f - 2.0f / (e + 1.0f);
    th = __builtin_copysignf(th, y);
    return 0.5f * v * (1.0f + th);
}

// async global->LDS, 16B per lane. LDS dest is wave-uniform base + lane*16.
__device__ __forceinline__ void gload16(const unsigned short* g, unsigned short* l) {
    __builtin_amdgcn_global_load_lds(
        (const __attribute__((address_space(1))) unsigned int*)g,
        (__attribute__((address_space(3))) unsigned int*)l,
        16, 0, 0);
}

// counted vmcnt wait (T4): allow newest N loads to stay in flight.
template<int N> __device__ __forceinline__ void vmwait() {
    asm volatile("s_waitcnt vmcnt(%0)" :: "n"(N) : "memory");
}
// raw barrier (no vmcnt drain) with compiler memory fences.
__device__ __forceinline__ void barrier_raw() {
    asm volatile("" ::: "memory");
    __builtin_amdgcn_s_barrier();
    asm volatile("" ::: "memory");
}

// ---------------- prep (blocks 0..623) + LayerNorm1 (blocks 624..4719) -----
__global__ __launch_bounds__(256) void prep_ln1(
    const float* __restrict__ Wq, const float* __restrict__ Wk,
    const float* __restrict__ Wv, const float* __restrict__ Wp,
    const float* __restrict__ W1, const float* __restrict__ W2,
    unsigned short* __restrict__ WqkvT, unsigned short* __restrict__ WpT,
    unsigned short* __restrict__ W1T, unsigned short* __restrict__ W2T,
    const float* __restrict__ xin, const float* __restrict__ gw,
    const float* __restrict__ bw, unsigned short* __restrict__ h1)
{
    __shared__ float smem[4096];
    const int bid = blockIdx.x, t = threadIdx.x;
    if (bid >= 624) {                    // ---- LN1: 4 rows per block
        int row  = (bid - 624) * 4 + (t >> 6);
        int lane = t & 63;
        const float4 v = *reinterpret_cast<const float4*>(xin + (size_t)row * 256 + lane * 4);
        float s  = v.x + v.y + v.z + v.w;
        float sq = v.x*v.x + v.y*v.y + v.z*v.z + v.w*v.w;
#pragma unroll
        for (int m = 1; m < 64; m <<= 1) { s += __shfl_xor(s, m); sq += __shfl_xor(sq, m); }
        float mean = s * (1.0f/256.0f);
        float var  = sq * (1.0f/256.0f) - mean*mean;
        float rstd = rsqrtf(var + 1e-5f);
        const float4 g4 = *reinterpret_cast<const float4*>(gw + lane*4);
        const float4 b4 = *reinterpret_cast<const float4*>(bw + lane*4);
        ushort4 o;
        o.x = f2bf((v.x-mean)*rstd*g4.x + b4.x);
        o.y = f2bf((v.y-mean)*rstd*g4.y + b4.y);
        o.z = f2bf((v.z-mean)*rstd*g4.z + b4.z);
        o.w = f2bf((v.w-mean)*rstd*g4.w + b4.w);
        *reinterpret_cast<ushort4*>(h1 + (size_t)row*256 + lane*4) = o;
        return;
    }
    if (bid < 576) {                     // ---- 32x32 tiled transposes
        const float* W; unsigned short* WT; int N, K, tile0;
        if (bid < 64)       { W = Wp; WT = WpT; N = 256;  K = 256;  tile0 = bid; }
        else if (bid < 320) { W = W1; WT = W1T; N = 1024; K = 256;  tile0 = bid - 64; }
        else                { W = W2; WT = W2T; N = 256;  K = 1024; tile0 = bid - 320; }
        int ntx = N >> 5;
        int bx = tile0 % ntx, by = tile0 / ntx;
        int c0 = bx*32, r0 = by*32;
        int tx = t & 31, ty = t >> 5;
#pragma unroll
        for (int i = 0; i < 4; ++i)
            smem[(ty + i*8)*33 + tx] = W[(size_t)(r0 + ty + i*8)*N + c0 + tx];
        __syncthreads();
#pragma unroll
        for (int i = 0; i < 4; ++i)
            WT[(size_t)(c0 + ty + i*8)*K + r0 + tx] = f2bf(smem[tx*33 + ty + i*8]);
    } else {                             // ---- QKV repack [H,C,HS] -> [768][256]
        int pb = bid - 576;
        int proj = pb >> 4, hh = pb & 15;
        const float* W = (proj == 0) ? Wq : ((proj == 1) ? Wk : Wv);
        float scale = (proj == 0) ? 0.0625f : 1.0f;
        const float4* src = reinterpret_cast<const float4*>(W + hh*4096);
#pragma unroll
        for (int i = 0; i < 4; ++i) {
            float4 v4 = src[t + i*256];
            *reinterpret_cast<float4*>(&smem[(t + i*256)*4]) = v4;
        }
        __syncthreads();
        int d = t >> 4, cp = (t & 15) * 16;
        unsigned short obuf[16];
#pragma unroll
        for (int i = 0; i < 16; ++i)
            obuf[i] = f2bf(smem[(cp + i)*16 + d] * scale);
        unsigned short* dst = WqkvT + (size_t)(proj*256 + hh*16 + d)*256 + cp;
        *reinterpret_cast<ushort4*>(dst)      = *reinterpret_cast<ushort4*>(&obuf[0]);
        *reinterpret_cast<ushort4*>(dst + 4)  = *reinterpret_cast<ushort4*>(&obuf[4]);
        *reinterpret_cast<ushort4*>(dst + 8)  = *reinterpret_cast<ushort4*>(&obuf[8]);
        *reinterpret_cast<ushort4*>(dst + 12) = *reinterpret_cast<ushort4*>(&obuf[12]);
    }
}

// XCD-aware bijective swizzle (T1): 1-D grid, nwg % 8 == 0.
template<int NBX>
__device__ __forceinline__ void swz_bid(int& bx, int& by) {
    int nwg = gridDim.x;
    int bid = blockIdx.x;
    int vid = (bid & 7) * (nwg >> 3) + (bid >> 3);
    bx = vid % NBX;
    by = vid / NBX;
}

// ------------- GEMM core, 4 waves (2x2), 3-buf counted-vmcnt pipeline ------
template<int BM, int BN, int K>
__device__ __forceinline__ void gemm_core(
    const unsigned short* __restrict__ A, const unsigned short* __restrict__ BT,
    int bx, int by, f32x4 (&acc)[BM/32][BN/32])
{
    constexpr int FM = BM/32, FN = BN/32, NT = K/32;
    constexpr int LA = BM/64, LB = BN/64, L = LA + LB;   // loads per thread per stage
    __shared__ unsigned short As[3][BM*32];
    __shared__ unsigned short Bs[3][BN*32];
    const int tid = threadIdx.x, lane = tid & 63, wid = tid >> 6;
    const int wr = (wid >> 1) * (BM/2), wc = (wid & 1) * (BN/2);
    const int c16 = lane & 15, g16 = lane >> 4;
    const int lr = lane >> 2, lq = lane & 3;

#pragma unroll
    for (int m = 0; m < FM; ++m)
#pragma unroll
        for (int n = 0; n < FN; ++n) acc[m][n] = f32x4{0.f, 0.f, 0.f, 0.f};

    const unsigned short* a0 = A  + (size_t)(by*BM + lr)*K + lq*8;
    const unsigned short* b0 = BT + (size_t)(bx*BN + lr)*K + lq*8;

    auto stage = [&](int buf, int t) {
        int k0 = t * 32;
#pragma unroll
        for (int i = 0; i < LA; ++i) {
            int ch = wid*LA + i;
            gload16(a0 + (size_t)ch*16*K + k0, &As[buf][ch*512]);
        }
#pragma unroll
        for (int i = 0; i < LB; ++i) {
            int ch = wid*LB + i;
            gload16(b0 + (size_t)ch*16*K + k0, &Bs[buf][ch*512]);
        }
    };

    auto compute = [&](int buf) {
        short8 af[FM], bf[FN];
#pragma unroll
        for (int m = 0; m < FM; ++m)
            af[m] = *reinterpret_cast<const short8*>(&As[buf][(wr + m*16 + c16)*32 + g16*8]);
#pragma unroll
        for (int n = 0; n < FN; ++n)
            bf[n] = *reinterpret_cast<const short8*>(&Bs[buf][(wc + n*16 + c16)*32 + g16*8]);
#pragma unroll
        for (int m = 0; m < FM; ++m)
#pragma unroll
            for (int n = 0; n < FN; ++n)
                acc[m][n] = __builtin_amdgcn_mfma_f32_16x16x32_bf16(af[m], bf[n], acc[m][n], 0, 0, 0);
    };

    stage(0, 0);
    stage(1, 1);
    int cur = 0;
    for (int t = 0; t < NT; ++t) {
        vmwait<L>();                     // tile t landed (tile t+1 may stay in flight)
        barrier_raw();                   // all waves' tile-t loads done; t-1 reads done
        if (t + 2 < NT) {
            int nb = cur + 2; if (nb >= 3) nb -= 3;
            stage(nb, t + 2);            // buffer last read at iter t-1
        }
        compute(cur);
        ++cur; if (cur == 3) cur = 0;
    }
}

// ------- GEMM core, 8 waves (2Mx4N), BN=256, 3-buf counted-vmcnt pipeline --
template<int BM, int BN, int K>
__device__ __forceinline__ void gemm_core8(
    const unsigned short* __restrict__ A, const unsigned short* __restrict__ BT,
    int bx, int by, f32x4 (&acc)[BM/32][BN/64])
{
    constexpr int FM = BM/32, FN = BN/64, NT = K/32;
    constexpr int NCHA = BM/16, NCH = BM/16 + BN/16;
    constexpr int NR = (NCH + 7) / 8;
    constexpr int NFULL = NCH / 8, NREM = NCH % 8;
    __shared__ unsigned short As[3][BM*32];
    __shared__ unsigned short Bs[3][BN*32];
    const int tid = threadIdx.x, lane = tid & 63, wid = tid >> 6;
    const int wm = wid >> 2, wn = wid & 3;
    const int c16 = lane & 15, g16 = lane >> 4;
    const int lr = lane >> 2, lq = lane & 3;

#pragma unroll
    for (int m = 0; m < FM; ++m)
#pragma unroll
        for (int n = 0; n < FN; ++n) acc[m][n] = f32x4{0.f, 0.f, 0.f, 0.f};

    const unsigned short* a0 = A  + (size_t)(by*BM + lr)*K + lq*8;
    const unsigned short* b0 = BT + (size_t)(bx*BN + lr)*K + lq*8;

    auto stage = [&](int buf, int t) {
        int k0 = t * 32;
#pragma unroll
        for (int i = 0; i < NR; ++i) {
            int ch = i*8 + wid;
            if (ch < NCHA)
                gload16(a0 + (size_t)ch*16*K + k0, &As[buf][ch*512]);
            else if (ch < NCH)
                gload16(b0 + (size_t)(ch-NCHA)*16*K + k0, &Bs[buf][(ch-NCHA)*512]);
        }
    };

    auto compute = [&](int buf) {
        short8 af[FM], bf[FN];
#pragma unroll
        for (int m = 0; m < FM; ++m)
            af[m] = *reinterpret_cast<const short8*>(&As[buf][(wm*(BM/2) + m*16 + c16)*32 + g16*8]);
#pragma unroll
        for (int n = 0; n < FN; ++n)
            bf[n] = *reinterpret_cast<const short8*>(&Bs[buf][(wn*(BN/4) + n*16 + c16)*32 + g16*8]);
#pragma unroll
        for (int m = 0; m < FM; ++m)
#pragma unroll
            for (int n = 0; n < FN; ++n)
                acc[m][n] = __builtin_amdgcn_mfma_f32_16x16x32_bf16(af[m], bf[n], acc[m][n], 0, 0, 0);
    };

    stage(0, 0);
    stage(1, 1);
    int cur = 0;
    for (int t = 0; t < NT; ++t) {
        if constexpr (NREM == 0) {
            vmwait<NFULL>();
        } else {                          // wave-uniform branch: per-wave load count
            if (wid < NREM) vmwait<NFULL + 1>();
            else            vmwait<NFULL>();
        }
        barrier_raw();
        if (t + 2 < NT) {
            int nb = cur + 2; if (nb >= 3) nb -= 3;
            stage(nb, t + 2);
        }
        compute(cur);
        ++cur; if (cur == 3) cur = 0;
    }
}

// QKV GEMM: N=768 = [q|k|v] x 16 heads x 16 dims; scatter epilogue.
__global__ __launch_bounds__(256) void gemm_qkv(
    const unsigned short* __restrict__ A, const unsigned short* __restrict__ BT,
    unsigned short* __restrict__ qb, unsigned short* __restrict__ kb,
    unsigned short* __restrict__ vtb)
{
    int bx, by; swz_bid<6>(bx, by);
    f32x4 acc[4][4];
    gemm_core<128, 128, 256>(A, BT, bx, by, acc);
    const int lane = threadIdx.x & 63, wid = threadIdx.x >> 6;
    const int c16 = lane & 15, g16 = lane >> 4;
    const int wr = (wid >> 1) * 64, wc = (wid & 1) * 64;
#pragma unroll
    for (int m = 0; m < 4; ++m)
#pragma unroll
    for (int n = 0; n < 4; ++n)
#pragma unroll
    for (int j = 0; j < 4; ++j) {
        int row = by*128 + wr + m*16 + g16*4 + j;
        int col = bx*128 + wc + n*16 + c16;
        int proj = col >> 8, hh = (col >> 4) & 15, dd = col & 15;
        int b = row >> 8, t = row & 255;
        unsigned short val = f2bf(acc[m][n][j]);
        size_t bh = (size_t)(b*16 + hh);
        if (proj == 0)      qb[(bh*256 + t)*16 + dd] = val;
        else if (proj == 1) kb[(bh*256 + t)*16 + dd] = val;
        else                vtb[(bh*16 + dd)*256 + t] = val;
    }
}

// proj GEMM + bias + residual -> x2 bf16, fused LN2 -> h2 bf16.
__global__ __launch_bounds__(512) void gemm_wp_ln(
    const unsigned short* __restrict__ A, const unsigned short* __restrict__ BT,
    const float* __restrict__ bp, const float* __restrict__ x,
    const float* __restrict__ g2, const float* __restrict__ be2,
    unsigned short* __restrict__ x2b, unsigned short* __restrict__ h2)
{
    int bx, by; swz_bid<1>(bx, by);
    f32x4 acc[2][4];
    gemm_core8<64, 256, 256>(A, BT, 0, by, acc);

    __shared__ float rs[64][4];
    __shared__ float rq[64][4];
    const int tid = threadIdx.x, lane = tid & 63, wid = tid >> 6;
    const int c16 = lane & 15, g16 = lane >> 4;
    const int wm = wid >> 2, wn = wid & 3;

    float vv[2][4][4];
#pragma unroll
    for (int m = 0; m < 2; ++m)
#pragma unroll
    for (int n = 0; n < 4; ++n)
#pragma unroll
    for (int j = 0; j < 4; ++j) {
        int row = by*64 + wm*32 + m*16 + g16*4 + j;
        int col = wn*64 + n*16 + c16;
        size_t idx = (size_t)row*256 + col;
        float v = acc[m][n][j] + bp[col] + x[idx];
        vv[m][n][j] = v;
        x2b[idx] = f2bf(v);
    }
#pragma unroll
    for (int m = 0; m < 2; ++m)
#pragma unroll
    for (int j = 0; j < 4; ++j) {
        float ps = vv[m][0][j] + vv[m][1][j] + vv[m][2][j] + vv[m][3][j];
        float pq = vv[m][0][j]*vv[m][0][j] + vv[m][1][j]*vv[m][1][j]
                 + vv[m][2][j]*vv[m][2][j] + vv[m][3][j]*vv[m][3][j];
#pragma unroll
        for (int mask = 1; mask < 16; mask <<= 1) {
            ps += __shfl_xor(ps, mask);
            pq += __shfl_xor(pq, mask);
        }
        if (c16 == 0) {
            int r = wm*32 + m*16 + g16*4 + j;
            rs[r][wn] = ps;
            rq[r][wn] = pq;
        }
    }
    __syncthreads();
#pragma unroll
    for (int m = 0; m < 2; ++m)
#pragma unroll
    for (int j = 0; j < 4; ++j) {
        int r = wm*32 + m*16 + g16*4 + j;
        float s = rs[r][0] + rs[r][1] + rs[r][2] + rs[r][3];
        float q = rq[r][0] + rq[r][1] + rq[r][2] + rq[r][3];
        float mean = s * (1.0f/256.0f);
        float var  = q * (1.0f/256.0f) - mean*mean;
        float rstd = rsqrtf(var + 1e-5f);
        int row = by*64 + r;
#pragma unroll
        for (int n = 0; n < 4; ++n) {
            int col = wn*64 + n*16 + c16;
            h2[(size_t)row*256 + col] = f2bf((vv[m][n][j]-mean)*rstd*g2[col] + be2[col]);
        }
    }
}

// FFN1 GEMM + bias + fast GELU -> bf16 [16384][1024]. 8 waves, 128x256 tile.
__global__ __launch_bounds__(512) void gemm_ffn1(
    const unsigned short* __restrict__ A, const unsigned short* __restrict__ BT,
    const float* __restrict__ b1, unsigned short* __restrict__ ffh)
{
    int bx, by; swz_bid<4>(bx, by);
    f32x4 acc[4][4];
    gemm_core8<128, 256, 256>(A, BT, bx, by, acc);
    const int lane = threadIdx.x & 63, wid = threadIdx.x >> 6;
    const int c16 = lane & 15, g16 = lane >> 4;
    const int wm = wid >> 2, wn = wid & 3;
#pragma unroll
    for (int m = 0; m < 4; ++m)
#pragma unroll
    for (int n = 0; n < 4; ++n)
#pragma unroll
    for (int j = 0; j < 4; ++j) {
        int row = by*128 + wm*64 + m*16 + g16*4 + j;
        int col = bx*256 + wn*64 + n*16 + c16;
        float v = acc[m][n][j] + b1[col];
        ffh[(size_t)row*1024 + col] = f2bf(fast_gelu(v));
    }
}

// FFN2 GEMM + bias + residual(x2 bf16) -> fp32 out. BM=64, BN=256, K=1024.
__global__ __launch_bounds__(512) void gemm_ffn2(
    const unsigned short* __restrict__ A, const unsigned short* __restrict__ BT,
    const float* __restrict__ b2, const unsigned short* __restrict__ x2b,
    float* __restrict__ out)
{
    int bx, by; swz_bid<1>(bx, by);
    f32x4 acc[2][4];
    gemm_core8<64, 256, 1024>(A, BT, 0, by, acc);
    const int lane = threadIdx.x & 63, wid = threadIdx.x >> 6;
    const int c16 = lane & 15, g16 = lane >> 4;
    const int wm = wid >> 2, wn = wid & 3;
#pragma unroll
    for (int m = 0; m < 2; ++m)
#pragma unroll
    for (int n = 0; n < 4; ++n)
#pragma unroll
    for (int j = 0; j < 4; ++j) {
        int row = by*64 + wm*32 + m*16 + g16*4 + j;
        int col = wn*64 + n*16 + c16;
        size_t idx = (size_t)row*256 + col;
        out[idx] = acc[m][n][j] + b2[col] + bf2f(x2b[idx]);
    }
}

// ---------------- Attention: register-resident, swapped 32x32x16 MFMA -----
__global__ __launch_bounds__(256) void attn_kernel(
    const unsigned short* __restrict__ qb, const unsigned short* __restrict__ kb,
    const unsigned short* __restrict__ vtb, unsigned short* __restrict__ ao)
{
    const int bid  = blockIdx.x;
    const int half = bid & 1, h = (bid >> 1) & 15, b = bid >> 5;
    const int tid  = threadIdx.x;
    const int w    = tid >> 6, lane = tid & 63;
    const int l31  = lane & 31, hi = lane >> 5;
    const int chunk = half*4 + w;
    const int t0    = chunk * 32;
    const unsigned short* qh = qb  + (size_t)(b*16 + h) * 4096;
    const unsigned short* kh = kb  + (size_t)(b*16 + h) * 4096;
    const unsigned short* vh = vtb + (size_t)(b*16 + h) * 4096;

    short8 qf = *reinterpret_cast<const short8*>(qh + (size_t)(t0 + l31)*16 + hi*8);

    f32x16 zf, pv;
#pragma unroll
    for (int i = 0; i < 16; ++i) { zf[i] = 0.f; pv[i] = 0.f; }
    float sum = 0.f;
    const int dref = l31 & 15;

    for (int tt = 0; tt <= chunk; ++tt) {
        short8 kf = *reinterpret_cast<const short8*>(kh + (size_t)(tt*32 + l31)*16 + hi*8);
        f32x16 S = __builtin_amdgcn_mfma_f32_32x32x16_bf16(kf, qf, zf, 0, 0, 0);

        float p[16];
#pragma unroll
        for (int r = 0; r < 16; ++r) {
            float pe = __expf(S[r]);
            if (tt == chunk) {
                int s_local = (r & 3) + 8*(r >> 2) + 4*hi;
                pe = (s_local <= l31) ? pe : 0.f;
            }
            p[r] = pe;
            sum += pe;
        }

        unsigned qd[8], xd[8];
#pragma unroll
        for (int i = 0; i < 8; ++i) {
            unsigned rr;
            asm("v_cvt_pk_bf16_f32 %0, %1, %2" : "=v"(rr) : "v"(p[2*i]), "v"(p[2*i+1]));
            qd[i] = rr;
        }
#pragma unroll
        for (int i = 0; i < 8; ++i) xd[i] = (unsigned)__shfl_xor((int)qd[i], 32);

        int4 flo, fhi;
        flo.x = hi ? (int)xd[2] : (int)qd[0];
        flo.y = hi ? (int)xd[3] : (int)qd[1];
        flo.z = hi ? (int)qd[2] : (int)xd[0];
        flo.w = hi ? (int)qd[3] : (int)xd[1];
        fhi.x = hi ? (int)xd[6] : (int)qd[4];
        fhi.y = hi ? (int)xd[7] : (int)qd[5];
        fhi.z = hi ? (int)qd[6] : (int)xd[4];
        fhi.w = hi ? (int)qd[7] : (int)xd[5];
        short8 plo = __builtin_bit_cast(short8, flo);
        short8 phi = __builtin_bit_cast(short8, fhi);

        short8 vf0 = *reinterpret_cast<const short8*>(vh + (size_t)dref*256 + tt*32 + hi*8);
        short8 vf1 = *reinterpret_cast<const short8*>(vh + (size_t)dref*256 + tt*32 + 16 + hi*8);
        pv = __builtin_amdgcn_mfma_f32_32x32x16_bf16(vf0, plo, pv, 0, 0, 0);
        pv = __builtin_amdgcn_mfma_f32_32x32x16_bf16(vf1, phi, pv, 0, 0, 0);
    }

    sum += __shfl_xor(sum, 32);
    float rinv = 1.0f / sum;

    unsigned o0, o1, o2, o3;
    {
        float a0 = pv[0]*rinv, a1 = pv[1]*rinv, a2 = pv[2]*rinv, a3 = pv[3]*rinv;
        float a4 = pv[4]*rinv, a5 = pv[5]*rinv, a6 = pv[6]*rinv, a7 = pv[7]*rinv;
        asm("v_cvt_pk_bf16_f32 %0, %1, %2" : "=v"(o0) : "v"(a0), "v"(a1));
        asm("v_cvt_pk_bf16_f32 %0, %1, %2" : "=v"(o1) : "v"(a2), "v"(a3));
        asm("v_cvt_pk_bf16_f32 %0, %1, %2" : "=v"(o2) : "v"(a4), "v"(a5));
        asm("v_cvt_pk_bf16_f32 %0, %1, %2" : "=v"(o3) : "v"(a6), "v"(a7));
    }
    unsigned short* orow = ao + (size_t)(b*256 + t0 + l31)*256 + h*16;
    uint2 s01 = {o0, o1}, s23 = {o2, o3};
    *reinterpret_cast<uint2*>(orow + hi*4)     = s01;
    *reinterpret_cast<uint2*>(orow + 8 + hi*4) = s23;
}

// ---------------- launch ---------------------------------------------------
extern "C" void kernel_launch(void* const* d_in, const int* in_sizes, int n_in,
                              void* d_out, int out_size, void* d_ws, size_t ws_size,
                              hipStream_t stream)
{
    const float* x   = (const float*)d_in[0];
    const float* Wq  = (const float*)d_in[1];
    const float* Wk  = (const float*)d_in[2];
    const float* Wv  = (const float*)d_in[3];
    const float* Wp  = (const float*)d_in[4];
    const float* bp  = (const float*)d_in[5];
    const float* W1  = (const float*)d_in[6];
    const float* b1  = (const float*)d_in[7];
    const float* W2  = (const float*)d_in[8];
    const float* b2  = (const float*)d_in[9];
    const float* g1  = (const float*)d_in[10];
    const float* be1 = (const float*)d_in[11];
    const float* g2  = (const float*)d_in[12];
    const float* be2 = (const float*)d_in[13];
    float* out = (float*)d_out;

    char* ws = (char*)d_ws;
    unsigned short* h1    = (unsigned short*)(ws);
    unsigned short* WqkvT = (unsigned short*)(ws +  8388608);
    unsigned short* WpT   = (unsigned short*)(ws +  8781824);
    unsigned short* W1T   = (unsigned short*)(ws +  8912896);
    unsigned short* W2T   = (unsigned short*)(ws +  9437184);
    unsigned short* qb    = (unsigned short*)(ws +  9961472);
    unsigned short* kb    = (unsigned short*)(ws + 18350080);
    unsigned short* vtb   = (unsigned short*)(ws + 26738688);
    unsigned short* ao    = (unsigned short*)(ws + 35127296);
    unsigned short* ffh   = qb;                       // aliases qb..ao (dead by FFN1)
    unsigned short* x2b   = (unsigned short*)(ws + 43515904);
    unsigned short* h2    = (unsigned short*)(ws + 60293120);

    prep_ln1<<<4720, 256, 0, stream>>>(Wq, Wk, Wv, Wp, W1, W2,
                                       WqkvT, WpT, W1T, W2T, x, g1, be1, h1);
    gemm_qkv<<<768, 256, 0, stream>>>(h1, WqkvT, qb, kb, vtb);
    attn_kernel<<<2048, 256, 0, stream>>>(qb, kb, vtb, ao);
    gemm_wp_ln<<<256, 512, 0, stream>>>(ao, WpT, bp, x, g2, be2, x2b, h2);
    gemm_ffn1<<<512, 512, 0, stream>>>(h2, W1T, b1, ffh);
    gemm_ffn2<<<256, 512, 0, stream>>>(ffh, W2T, b2, x2b, out);
}